// Round 2
// baseline (902.738 us; speedup 1.0000x reference)
//
#include <hip/hip_runtime.h>
#include <math.h>

#define NN 100000
#define NE 1600000
#define NG 64
#define CC 64
#define KK 128
#define EPSI 1e-5f

// ---- workspace layout (float offsets) ----
#define WS_H     0          // h[NN*64]            25.6 MB
#define WS_P     6400000    // p[NN*8]  row/col head projections
#define WS_DEG   7200000    // deg[NN]
#define WS_DINV  7300000    // dinv[NN]
#define WS_MEAN  7400000    // mean[NG*64]
#define WS_RINV  7404096    // rinv[NG*64]
#define WS_START 7408192    // int start[NG+1]

// ---- output layout (float offsets) ----
#define OUT_ALPHA 6400000
#define OUT_IDX   8000000

// h = x @ W, wave-per-row, W staged in LDS (32 KB)
__global__ __launch_bounds__(256) void k_gemm(const float* __restrict__ x,
                                              const float* __restrict__ w,
                                              float* __restrict__ h) {
    __shared__ float wl[KK * CC];
    for (int i = threadIdx.x; i < KK * CC; i += 256) wl[i] = w[i];
    __syncthreads();
    int lane = threadIdx.x & 63;
    int wid  = (blockIdx.x * 256 + threadIdx.x) >> 6;
    int nw   = (gridDim.x * 256) >> 6;
    for (int row = wid; row < NN; row += nw) {
        const float* xr = x + (size_t)row * KK;
        float acc = 0.f;
        #pragma unroll
        for (int k = 0; k < KK; k += 4) {
            float4 xv = *reinterpret_cast<const float4*>(xr + k);  // wave-uniform, L1 broadcast
            acc += xv.x * wl[(k + 0) * CC + lane];
            acc += xv.y * wl[(k + 1) * CC + lane];
            acc += xv.z * wl[(k + 2) * CC + lane];
            acc += xv.w * wl[(k + 3) * CC + lane];
        }
        h[(size_t)row * CC + lane] = acc;
    }
}

// graph start offsets from sorted batch_mask; start[g]..start[g+1] = rows of graph g
__global__ void k_starts(const int* __restrict__ bm, int* __restrict__ start) {
    int i = blockIdx.x * blockDim.x + threadIdx.x;
    if (i > NN) return;
    if (i == 0) {
        int b = bm[0];
        for (int g = 0; g <= b; ++g) start[g] = 0;
    } else if (i == NN) {
        int b = bm[NN - 1];
        for (int g = b + 1; g <= NG; ++g) start[g] = NN;
    } else {
        int b0 = bm[i - 1], b1 = bm[i];
        for (int g = b0 + 1; g <= b1; ++g) start[g] = i;
    }
}

// per-graph per-channel mean / rsqrt(var+eps); one block per graph, lane = channel
__global__ __launch_bounds__(256) void k_stats(const float* __restrict__ h,
                                               const int* __restrict__ start,
                                               float* __restrict__ meanb,
                                               float* __restrict__ rinvb) {
    __shared__ float ssum[4][64], ssq[4][64];
    int g = blockIdx.x;
    int s = start[g], e = start[g + 1];
    int w = threadIdx.x >> 6, lane = threadIdx.x & 63;
    float a = 0.f, b = 0.f;
    for (int r = s + w; r < e; r += 4) {
        float v = h[(size_t)r * CC + lane];
        a += v; b += v * v;
    }
    ssum[w][lane] = a; ssq[w][lane] = b;
    __syncthreads();
    if (w == 0) {
        a = ssum[0][lane] + ssum[1][lane] + ssum[2][lane] + ssum[3][lane];
        b = ssq[0][lane] + ssq[1][lane] + ssq[2][lane] + ssq[3][lane];
        float mean = 0.f, rinv = 0.f;
        if (e > s) {
            float cnt = (float)(e - s);
            mean = a / cnt;
            float var = b / cnt - mean * mean;
            rinv = rsqrtf(var + EPSI);
        }
        meanb[g * 64 + lane] = mean;
        rinvb[g * 64 + lane] = rinv;
    }
}

// h = (h - mean[g]) * rinv[g], float4 per thread
__global__ void k_norm(float* __restrict__ h, const int* __restrict__ bm,
                       const float* __restrict__ meanb, const float* __restrict__ rinvb) {
    int id = blockIdx.x * blockDim.x + threadIdx.x;
    if (id >= NN * 16) return;
    int i = id >> 4, c4 = (id & 15) << 2;
    int g = bm[i];
    float4 v = *reinterpret_cast<float4*>(h + (size_t)i * CC + c4);
    float4 m = *reinterpret_cast<const float4*>(meanb + g * 64 + c4);
    float4 r = *reinterpret_cast<const float4*>(rinvb + g * 64 + c4);
    v.x = (v.x - m.x) * r.x;
    v.y = (v.y - m.y) * r.y;
    v.z = (v.z - m.z) * r.z;
    v.w = (v.w - m.w) * r.w;
    *reinterpret_cast<float4*>(h + (size_t)i * CC + c4) = v;
}

// per-node head projections: p[n][j] : j<4 = h[n].aw[j][0:64], j>=4 = h[n].aw[j-4][64:128]
__global__ __launch_bounds__(256) void k_proj(const float* __restrict__ h,
                                              const float* __restrict__ aw,
                                              float* __restrict__ p) {
    __shared__ float awl[4 * KK];
    for (int i = threadIdx.x; i < 4 * KK; i += 256) awl[i] = aw[i];
    __syncthreads();
    int id = blockIdx.x * 256 + threadIdx.x;
    int n = id >> 3, j = id & 7;
    if (n >= NN) return;
    int hd = j & 3, half = (j >> 2) * 64;
    const float* hr = h + (size_t)n * CC;
    float acc = 0.f;
    #pragma unroll
    for (int c = 0; c < CC; c += 4) {
        float4 v = *reinterpret_cast<const float4*>(hr + c);
        acc += v.x * awl[hd * KK + half + c + 0];
        acc += v.y * awl[hd * KK + half + c + 1];
        acc += v.z * awl[hd * KK + half + c + 2];
        acc += v.w * awl[hd * KK + half + c + 3];
    }
    p[(size_t)n * 8 + j] = acc;
}

// per-edge attention: alpha = mean_h sigmoid(p_row[row][h]+p_col[col][h]+b[h])*ea, self-loop -> 1
__global__ __launch_bounds__(256) void k_alpha(const float* __restrict__ p,
                                               const int* __restrict__ ei,
                                               const float* __restrict__ ab,
                                               const float* __restrict__ ea,
                                               float* __restrict__ alpha_out,
                                               float* __restrict__ deg) {
    int e = blockIdx.x * 256 + threadIdx.x;
    if (e >= NE) return;
    int row = ei[e], col = ei[NE + e];
    float a;
    if (row == col) {
        a = 1.f;
    } else {
        float4 pr = *reinterpret_cast<const float4*>(p + (size_t)row * 8);
        float4 pc = *reinterpret_cast<const float4*>(p + (size_t)col * 8 + 4);
        float4 bb = *reinterpret_cast<const float4*>(ab);
        float ev = ea[e];
        float s0 = ev / (1.f + __expf(-(pr.x + pc.x + bb.x)));
        float s1 = ev / (1.f + __expf(-(pr.y + pc.y + bb.y)));
        float s2 = ev / (1.f + __expf(-(pr.z + pc.z + bb.z)));
        float s3 = ev / (1.f + __expf(-(pr.w + pc.w + bb.w)));
        a = 0.25f * (s0 + s1 + s2 + s3);
    }
    alpha_out[e] = a;
    atomicAdd(deg + row, fabsf(a));
}

__global__ void k_dinv(const float* __restrict__ deg, float* __restrict__ dinv) {
    int n = blockIdx.x * blockDim.x + threadIdx.x;
    if (n >= NN) return;
    float d = deg[n];
    dinv[n] = (d > 0.f) ? rsqrtf(d) : 0.f;
}

// wave-per-edge scatter: out[row] += dinv[row]*alpha*dinv[col] * h[col]
__global__ __launch_bounds__(256) void k_scatter(const float* __restrict__ h,
                                                 const int* __restrict__ ei,
                                                 const float* __restrict__ alpha,
                                                 const float* __restrict__ dinv,
                                                 float* __restrict__ out) {
    int lane = threadIdx.x & 63;
    int wid  = (blockIdx.x * 256 + threadIdx.x) >> 6;
    int nw   = (gridDim.x * 256) >> 6;
    for (int e = wid; e < NE; e += nw) {
        int row = ei[e], col = ei[NE + e];
        float nrm = dinv[row] * alpha[e] * dinv[col];
        float v = nrm * h[(size_t)col * CC + lane];
        atomicAdd(out + (size_t)row * CC + lane, v);
    }
}

__global__ void k_idx(const int* __restrict__ ei, float* __restrict__ o) {
    int i = blockIdx.x * blockDim.x + threadIdx.x;
    if (i >= 2 * NE) return;
    o[i] = (float)ei[i];
}

extern "C" void kernel_launch(void* const* d_in, const int* in_sizes, int n_in,
                              void* d_out, int out_size, void* d_ws, size_t ws_size,
                              hipStream_t stream) {
    const float* x  = (const float*)d_in[0];
    const float* w  = (const float*)d_in[1];
    const float* aw = (const float*)d_in[2];
    const float* ab = (const float*)d_in[3];
    const float* ea = (const float*)d_in[4];
    const int*   ei = (const int*)d_in[5];
    const int*   bm = (const int*)d_in[6];
    float* out = (float*)d_out;
    float* ws  = (float*)d_ws;
    float* h     = ws + WS_H;
    float* p     = ws + WS_P;
    float* deg   = ws + WS_DEG;
    float* dinv  = ws + WS_DINV;
    float* meanb = ws + WS_MEAN;
    float* rinvb = ws + WS_RINV;
    int*   start = (int*)(ws + WS_START);

    hipMemsetAsync(out, 0, (size_t)6400000 * 4, stream);   // out accumulator region
    hipMemsetAsync(deg, 0, (size_t)NN * 4, stream);

    k_gemm  <<<2500, 256, 0, stream>>>(x, w, h);
    k_starts<<<(NN + 256) / 256, 256, 0, stream>>>(bm, start);
    k_stats <<<NG, 256, 0, stream>>>(h, start, meanb, rinvb);
    k_norm  <<<(NN * 16 + 255) / 256, 256, 0, stream>>>(h, bm, meanb, rinvb);
    k_proj  <<<(NN * 8 + 255) / 256, 256, 0, stream>>>(h, aw, p);
    k_alpha <<<(NE + 255) / 256, 256, 0, stream>>>(p, ei, ab, ea, out + OUT_ALPHA, deg);
    k_dinv  <<<(NN + 255) / 256, 256, 0, stream>>>(deg, dinv);
    k_scatter<<<25600, 256, 0, stream>>>(h, ei, out + OUT_ALPHA, dinv, out);
    k_idx   <<<(2 * NE + 255) / 256, 256, 0, stream>>>(ei, out + OUT_IDX);
}